// Round 1
// baseline (164.459 us; speedup 1.0000x reference)
//
#include <hip/hip_runtime.h>

// Problem constants: x is (B=16, C=256, H=128, W=128) f32, NCHW.
#define NB 16
#define NC 256
#define NH 128
#define NW 128
#define PLANE (NH*NW)          // 16384 elements per (b,c) plane
#define PLANE4 (PLANE/4)       // 4096 float4 per plane

// Kernel 1: s[b,h,w] = sum_c x[b,c,h,w].  One thread per float4 of s.
// Total threads = NB*PLANE4 = 65536.  Each does 256 float4 loads at 64 KiB
// stride (wave-load = 1 KiB contiguous -> fully coalesced).
__global__ __launch_bounds__(256) void sum_channels(const float* __restrict__ x,
                                                    float* __restrict__ s) {
    int i4  = blockIdx.x * blockDim.x + threadIdx.x;   // 0 .. 65535
    int b   = i4 >> 12;                                // / PLANE4
    int rem = i4 & (PLANE4 - 1);
    const float4* xp = (const float4*)x + (size_t)b * NC * PLANE4 + rem;
    float4 acc = make_float4(0.f, 0.f, 0.f, 0.f);
#pragma unroll 8
    for (int c = 0; c < NC; ++c) {
        float4 v = xp[(size_t)c * PLANE4];
        acc.x += v.x; acc.y += v.y; acc.z += v.z; acc.w += v.w;
    }
    ((float4*)s)[i4] = acc;
}

// Kernel 2: x1 = conv3x3(s) with zero padding=1 (cross-correlation, OIHW
// weights, no flip).  s and filters are tiny -> L2-resident.
__global__ __launch_bounds__(256) void conv3x3(const float* __restrict__ s,
                                               const float* __restrict__ f,
                                               float* __restrict__ x1) {
    int i  = blockIdx.x * blockDim.x + threadIdx.x;    // 0 .. NB*PLANE-1
    int b  = i >> 14;                                  // / PLANE
    int hw = i & (PLANE - 1);
    int h  = hw >> 7;
    int w  = hw & (NW - 1);
    const float* sp = s + (size_t)b * PLANE;
    float acc = 0.f;
#pragma unroll
    for (int kh = 0; kh < 3; ++kh) {
        int hh = h + kh - 1;
        if (hh < 0 || hh >= NH) continue;
#pragma unroll
        for (int kw = 0; kw < 3; ++kw) {
            int ww = w + kw - 1;
            if (ww < 0 || ww >= NW) continue;
            acc += sp[hh * NW + ww] * f[kh * 3 + kw];
        }
    }
    x1[i] = acc;
}

// Kernel 3: out[b,c,h,w] = x[b,c,h,w] - x1[b,h,w].  Grid-stride float4.
// x1 float4 is re-read 256x per pixel -> L2 broadcast, ~free.
__global__ __launch_bounds__(256) void subtract(const float* __restrict__ x,
                                                const float* __restrict__ x1,
                                                float* __restrict__ out,
                                                int total4) {
    int stride = gridDim.x * blockDim.x;
    for (int i4 = blockIdx.x * blockDim.x + threadIdx.x; i4 < total4; i4 += stride) {
        int plane = i4 >> 12;            // b*NC + c
        int rem   = i4 & (PLANE4 - 1);
        int b     = plane >> 8;          // / NC
        float4 xv = ((const float4*)x)[i4];
        float4 cv = ((const float4*)x1)[b * PLANE4 + rem];
        float4 o  = make_float4(xv.x - cv.x, xv.y - cv.y, xv.z - cv.z, xv.w - cv.w);
        ((float4*)out)[i4] = o;
    }
}

extern "C" void kernel_launch(void* const* d_in, const int* in_sizes, int n_in,
                              void* d_out, int out_size, void* d_ws, size_t ws_size,
                              hipStream_t stream) {
    const float* x       = (const float*)d_in[0];
    const float* filters = (const float*)d_in[1];
    float*       out     = (float*)d_out;

    // Workspace layout: s = NB*PLANE floats (1 MiB), x1 = NB*PLANE floats (1 MiB)
    float* s  = (float*)d_ws;
    float* x1 = s + NB * PLANE;

    // Kernel 1: 65536 threads = 256 blocks x 256
    sum_channels<<<(NB * PLANE4) / 256, 256, 0, stream>>>(x, s);

    // Kernel 2: 262144 threads = 1024 blocks x 256
    conv3x3<<<(NB * PLANE) / 256, 256, 0, stream>>>(s, filters, x1);

    // Kernel 3: grid-stride, 2048 blocks x 256 threads
    int total4 = out_size / 4;           // 16777216 float4
    subtract<<<2048, 256, 0, stream>>>(x, x1, out, total4);
}

// Round 2
// 145.655 us; speedup vs baseline: 1.1291x; 1.1291x over previous
//
#include <hip/hip_runtime.h>

// x: (B=16, C=256, H=128, W=128) f32 NCHW.
#define NB 16
#define NC 256
#define NH 128
#define NW 128
#define PLANE (NH*NW)          // 16384
#define PLANE4 (PLANE/4)       // 4096
#define NSPLIT 4
#define CPS (NC/NSPLIT)        // 64 channels per split

typedef float v4f __attribute__((ext_vector_type(4)));

// Kernel 1: partial channel sums, 4-way channel split for occupancy.
// 262144 threads = 1024 blocks (4 blocks/CU, 16 waves/CU).
// partial[chunk][b][hw] : chunk-stride NB*PLANE floats. 4 MiB total in ws.
__global__ __launch_bounds__(256) void sum_partial(const float* __restrict__ x,
                                                   float* __restrict__ partial) {
    int i     = blockIdx.x * blockDim.x + threadIdx.x;   // 0 .. 262143
    int i4    = i & (NB * PLANE4 - 1);                   // (b, rem)
    int chunk = i >> 16;                                 // 0..3
    int b     = i4 >> 12;
    int rem   = i4 & (PLANE4 - 1);
    const float4* xp = (const float4*)x + ((size_t)b * NC + (size_t)chunk * CPS) * PLANE4 + rem;
    float4 acc = make_float4(0.f, 0.f, 0.f, 0.f);
#pragma unroll 8
    for (int c = 0; c < CPS; ++c) {
        float4 v = xp[(size_t)c * PLANE4];
        acc.x += v.x; acc.y += v.y; acc.z += v.z; acc.w += v.w;
    }
    ((float4*)partial)[(size_t)chunk * (NB * PLANE4) + i4] = acc;
}

// Kernel 2: reduce 4 partials + conv3x3 (zero-pad 1, cross-correlation).
// All reads L2-resident (partials = 4 MiB). Writes x1 (1 MiB). ~5 us.
__global__ __launch_bounds__(256) void conv3x3(const float* __restrict__ partial,
                                               const float* __restrict__ f,
                                               float* __restrict__ x1) {
    int i  = blockIdx.x * blockDim.x + threadIdx.x;      // 0 .. NB*PLANE-1
    int b  = i >> 14;
    int hw = i & (PLANE - 1);
    int h  = hw >> 7;
    int w  = hw & (NW - 1);
    const float* pb = partial + (size_t)b * PLANE;
    float acc = 0.f;
#pragma unroll
    for (int kh = 0; kh < 3; ++kh) {
        int hh = h + kh - 1;
        if (hh < 0 || hh >= NH) continue;
#pragma unroll
        for (int kw = 0; kw < 3; ++kw) {
            int ww = w + kw - 1;
            if (ww < 0 || ww >= NW) continue;
            int idx = hh * NW + ww;
            float s = pb[idx]
                    + pb[1 * (NB * PLANE) + idx]
                    + pb[2 * (NB * PLANE) + idx]
                    + pb[3 * (NB * PLANE) + idx];
            acc += s * f[kh * 3 + kw];
        }
    }
    x1[i] = acc;
}

// Kernel 3: out = x - broadcast(x1). Non-temporal stores on out so the 256 MiB
// write stream does not evict x from the 256 MiB Infinity Cache -> next
// replay's sum_partial re-reads x from L3 instead of HBM.
__global__ __launch_bounds__(256) void subtract(const float* __restrict__ x,
                                                const float* __restrict__ x1,
                                                float* __restrict__ out,
                                                int total4) {
    int stride = gridDim.x * blockDim.x;
    for (int i4 = blockIdx.x * blockDim.x + threadIdx.x; i4 < total4; i4 += stride) {
        int plane = i4 >> 12;            // b*NC + c
        int rem   = i4 & (PLANE4 - 1);
        int b     = plane >> 8;
        v4f xv = *(const v4f*)((const float4*)x + i4);
        v4f cv = *(const v4f*)((const float4*)x1 + b * PLANE4 + rem);
        v4f o  = xv - cv;
        __builtin_nontemporal_store(o, (v4f*)((float4*)out + i4));
    }
}

extern "C" void kernel_launch(void* const* d_in, const int* in_sizes, int n_in,
                              void* d_out, int out_size, void* d_ws, size_t ws_size,
                              hipStream_t stream) {
    const float* x       = (const float*)d_in[0];
    const float* filters = (const float*)d_in[1];
    float*       out     = (float*)d_out;

    // ws layout: partial = NSPLIT*NB*PLANE floats (4 MiB), x1 = NB*PLANE (1 MiB)
    float* partial = (float*)d_ws;
    float* x1      = partial + (size_t)NSPLIT * NB * PLANE;

    sum_partial<<<(NSPLIT * NB * PLANE4) / 256, 256, 0, stream>>>(x, partial);
    conv3x3<<<(NB * PLANE) / 256, 256, 0, stream>>>(partial, filters, x1);

    int total4 = out_size / 4;           // 16777216
    subtract<<<2048, 256, 0, stream>>>(x, x1, out, total4);
}

// Round 3
// 138.998 us; speedup vs baseline: 1.1832x; 1.0479x over previous
//
#include <hip/hip_runtime.h>

// x: (B=16, C=256, H=128, W=128) f32 NCHW.
#define NB 16
#define NC 256
#define NH 128
#define NW 128
#define PLANE (NH*NW)          // 16384
#define PLANE4 (PLANE/4)       // 4096
#define NSPLIT 4
#define CPS (NC/NSPLIT)        // 64 channels per split

typedef float v4f __attribute__((ext_vector_type(4)));

// Kernel 1: partial channel sums, 4-way channel split for occupancy.
// 1024 blocks x 256 thr (16 waves/CU). Reads all of x (256 MiB) -> x resident
// in L3 at kernel end. Regular (temporal) loads on purpose.
__global__ __launch_bounds__(256) void sum_partial(const float* __restrict__ x,
                                                   float* __restrict__ partial) {
    int i     = blockIdx.x * blockDim.x + threadIdx.x;   // 0 .. 262143
    int i4    = i & (NB * PLANE4 - 1);                   // (b, rem)
    int chunk = i >> 16;                                 // 0..3
    int b     = i4 >> 12;
    int rem   = i4 & (PLANE4 - 1);
    const float4* xp = (const float4*)x + ((size_t)b * NC + (size_t)chunk * CPS) * PLANE4 + rem;
    float4 acc = make_float4(0.f, 0.f, 0.f, 0.f);
#pragma unroll 8
    for (int c = 0; c < CPS; ++c) {
        float4 v = xp[(size_t)c * PLANE4];
        acc.x += v.x; acc.y += v.y; acc.z += v.z; acc.w += v.w;
    }
    ((float4*)partial)[(size_t)chunk * (NB * PLANE4) + i4] = acc;
}

// Kernel 2: reduce 4 partials + conv3x3 (zero-pad 1, cross-correlation).
// Reads 4 MiB (L2/L3-hit), writes x1 (1 MiB). ~4 us.
__global__ __launch_bounds__(256) void conv3x3(const float* __restrict__ partial,
                                               const float* __restrict__ f,
                                               float* __restrict__ x1) {
    int i  = blockIdx.x * blockDim.x + threadIdx.x;      // 0 .. NB*PLANE-1
    int b  = i >> 14;
    int hw = i & (PLANE - 1);
    int h  = hw >> 7;
    int w  = hw & (NW - 1);
    const float* pb = partial + (size_t)b * PLANE;
    float acc = 0.f;
#pragma unroll
    for (int kh = 0; kh < 3; ++kh) {
        int hh = h + kh - 1;
        if (hh < 0 || hh >= NH) continue;
#pragma unroll
        for (int kw = 0; kw < 3; ++kw) {
            int ww = w + kw - 1;
            if (ww < 0 || ww >= NW) continue;
            int idx = hh * NW + ww;
            float s = pb[idx]
                    + pb[1 * (NB * PLANE) + idx]
                    + pb[2 * (NB * PLANE) + idx]
                    + pb[3 * (NB * PLANE) + idx];
            acc += s * f[kh * 3 + kw];
        }
    }
    x1[i] = acc;
}

// Kernel 3: out = x - broadcast(x1), iterated in REVERSE slab order.
// k1 left x resident in the 256 MiB L3 with head=LRU, tail=MRU. Out-writes
// allocate and evict from the LRU (head) end; by reading tail-first we consume
// the MRU end while evictions eat the head -> ~50% L3 hits instead of ~0%
// (forward order chases its own evictions). x loads are non-temporal so miss
// fills don't allocate and steal residency from data ahead; out stores are
// non-temporal so the write stream allocates as weakly as the HW allows.
__global__ __launch_bounds__(256) void subtract(const float* __restrict__ x,
                                                const float* __restrict__ x1,
                                                float* __restrict__ out,
                                                int total4) {
    int gid    = blockIdx.x * blockDim.x + threadIdx.x;
    int stride = gridDim.x * blockDim.x;                 // 524288
    for (int base = ((total4 - 1) / stride) * stride; base >= 0; base -= stride) {
        int i4 = base + gid;
        if (i4 >= total4) continue;
        int plane = i4 >> 12;            // b*NC + c
        int rem   = i4 & (PLANE4 - 1);
        int b     = plane >> 8;
        v4f xv = __builtin_nontemporal_load((const v4f*)((const float4*)x + i4));
        v4f cv = *(const v4f*)((const float4*)x1 + b * PLANE4 + rem);
        v4f o  = xv - cv;
        __builtin_nontemporal_store(o, (v4f*)((float4*)out + i4));
    }
}

extern "C" void kernel_launch(void* const* d_in, const int* in_sizes, int n_in,
                              void* d_out, int out_size, void* d_ws, size_t ws_size,
                              hipStream_t stream) {
    const float* x       = (const float*)d_in[0];
    const float* filters = (const float*)d_in[1];
    float*       out     = (float*)d_out;

    // ws layout: partial = NSPLIT*NB*PLANE floats (4 MiB), x1 = NB*PLANE (1 MiB)
    float* partial = (float*)d_ws;
    float* x1      = partial + (size_t)NSPLIT * NB * PLANE;

    sum_partial<<<(NSPLIT * NB * PLANE4) / 256, 256, 0, stream>>>(x, partial);
    conv3x3<<<(NB * PLANE) / 256, 256, 0, stream>>>(partial, filters, x1);

    int total4 = out_size / 4;           // 16777216
    subtract<<<2048, 256, 0, stream>>>(x, x1, out, total4);
}